// Round 8
// baseline (340.888 us; speedup 1.0000x reference)
//
#include <hip/hip_runtime.h>
#include <hip/hip_cooperative_groups.h>
#include <type_traits>

namespace cg = cooperative_groups;

typedef unsigned short u16;
typedef __attribute__((ext_vector_type(8))) short short8;
typedef __attribute__((ext_vector_type(4))) float floatx4;

__device__ __forceinline__ u16 f2u(float f) {
  unsigned int x = __float_as_uint(f);
  x += 0x7fff + ((x >> 16) & 1);  // RNE to bf16
  return (u16)(x >> 16);
}

__device__ __forceinline__ void async16(const void* g, void* l) {
  __builtin_amdgcn_global_load_lds(
      (const __attribute__((address_space(1))) unsigned int*)g,
      (__attribute__((address_space(3))) unsigned int*)l, 16, 0, 0);
}

// Round-7 proven TN GEMM body: C[m][col] = sum_k A[m][k]*B[col][k].
// BM=BN=32; 4 waves 2x2, one 16x16 acc each. Macro BK=256 (8 k32-subtiles),
// double-buffered LDS (lA/lB = 16KB x 2 bufs each), ONE barrier per macro.
template <bool SCALE_D, bool RESIDUAL, typename CT>
__device__ __forceinline__ void gemm32_body(
    u16* lA, u16* lB, const u16* __restrict__ A, const u16* __restrict__ B,
    CT* __restrict__ C, int M, int NN, int K, int m0, int n0,
    const float* __restrict__ lam, const float* __restrict__ pa,
    const float* __restrict__ pb, const float* __restrict__ pc,
    const float* __restrict__ resid, float alpha) {
  const int t = threadIdx.x;
  const int wave = t >> 6, lane = t & 63;
  const int wm = wave >> 1, wn = wave & 1;
  const int q = lane >> 4, l15 = lane & 15;

  const int within = t & 127, st0 = t >> 7;  // st0 in {0,1}
  const u16* gA = A + (size_t)(m0 + (within >> 2)) * K + (within & 3) * 8;
  const u16* gB = B + (size_t)(n0 + (within >> 2)) * K + (within & 3) * 8;
  char* lAc = (char*)lA;
  char* lBc = (char*)lB;

  const int NM = K >> 8;  // macro-iters (K/256)

  auto issue = [&](int i, int buf) {
    int k0 = i * 256;
#pragma unroll
    for (int p = 0; p < 4; ++p) {
      int st = 2 * p + st0;
      async16(gA + k0 + st * 32, lAc + buf * 16384 + p * 4096 + t * 16);
      async16(gB + k0 + st * 32, lBc + buf * 16384 + p * 4096 + t * 16);
    }
  };

  floatx4 acc = (floatx4){0.f, 0.f, 0.f, 0.f};

  issue(0, 0);
  for (int i = 0; i < NM; ++i) {
    const int buf = i & 1;
    __syncthreads();  // drains buf's prefetch; all waves done with buf^1
    if (i + 1 < NM) issue(i + 1, buf ^ 1);
    const u16* lAb = lA + buf * 8192;  // u16 units
    const u16* lBb = lB + buf * 8192;
#pragma unroll
    for (int st = 0; st < 8; ++st) {
      short8 af = *(const short8*)&lAb[st * 1024 + (wm * 16 + l15) * 32 + q * 8];
      short8 bf = *(const short8*)&lBb[st * 1024 + (wn * 16 + l15) * 32 + q * 8];
      acc = __builtin_amdgcn_mfma_f32_16x16x32_bf16(af, bf, acc, 0, 0, 0);
    }
  }

  // C/D layout: col=lane&15, row=(lane>>4)*4+reg  [m89/m91]
  const int col = n0 + wn * 16 + l15;
  float ds = 1.f;
  if (SCALE_D) {
    float lv = lam[(size_t)col * NN + col];
    float dacc = 0.f;
#pragma unroll
    for (int i = 0; i < 4; ++i) {
      float ai = pa[i], bi = pb[i], ci = pc[i];
      float rep = (ai - lv) * (lv - bi);
      rep = rep > 0.f ? rep : 0.f;
      dacc += ci * 4.f / ((ai - bi) * (ai - bi)) * rep;
    }
    ds = dacc;
  }
  const int rbase = m0 + wm * 16 + q * 4;
#pragma unroll
  for (int r = 0; r < 4; ++r) {
    float v = acc[r];
    if (SCALE_D) v *= ds;
    size_t idx = (size_t)(rbase + r) * NN + col;
    if (RESIDUAL) v += alpha * resid[idx];
    if constexpr (std::is_same<CT, u16>::value)
      C[idx] = f2u(v);
    else
      C[idx] = v;
  }
}

// One cooperative dispatch, 512 blocks x 256 thr, 64KB LDS (2 blocks/CU):
//  Phase P: 1152 transpose-cast jobs (U->Ut+Ubf, x->xT), grid-strided
//  Phase G1: zT[f][j] = d[j]*sum_n xT[f][n]*Ut[j][n]   (8x64 tile map)
//  Phase G2: out[n][f] = alpha*x[n][f]+sum_j Ubf[n][j]*zT[f][j] (64x8 map)
__global__ __launch_bounds__(256) void mega_kernel(
    const float* __restrict__ U, const float* __restrict__ x,
    const float* __restrict__ lam, const float* __restrict__ a,
    const float* __restrict__ b, const float* __restrict__ c,
    const float* __restrict__ alpha_p, float* __restrict__ out,
    u16* __restrict__ xT, u16* __restrict__ Ut, u16* __restrict__ Ubf,
    u16* __restrict__ zT) {
  __shared__ __attribute__((aligned(16))) char smem[65536];
  const int t = threadIdx.x;
  const int N = 2048, F = 256;

  // ---- Phase P: transpose+cast (round-7 prep body, grid-strided) ----
  {
    float(*tile)[65] = (float(*)[65])smem;
    for (int bb = blockIdx.x; bb < 1152; bb += gridDim.x) {
      const float* in;
      u16 *outT, *outC;
      int C_, c0, r0;
      if (bb < 1024) {  // U job
        in = U; outT = Ut; outC = Ubf; C_ = N;
        c0 = (bb & 31) * 64; r0 = (bb >> 5) * 64;
      } else {  // x job
        int b2 = bb - 1024;
        in = x; outT = xT; outC = nullptr; C_ = F;
        c0 = (b2 & 3) * 64; r0 = (b2 >> 2) * 64;
      }
#pragma unroll
      for (int p = 0; p < 4; ++p) {
        int e = p * 256 + t;
        int row = e >> 4, col = (e & 15) * 4;
        float4 v = *(const float4*)(in + (size_t)(r0 + row) * C_ + c0 + col);
        tile[row][col] = v.x;
        tile[row][col + 1] = v.y;
        tile[row][col + 2] = v.z;
        tile[row][col + 3] = v.w;
        if (outC) {
          union { uint2 u; u16 s[4]; } pk;
          pk.s[0] = f2u(v.x); pk.s[1] = f2u(v.y);
          pk.s[2] = f2u(v.z); pk.s[3] = f2u(v.w);
          *(uint2*)(outC + (size_t)(r0 + row) * C_ + c0 + col) = pk.u;
        }
      }
      __syncthreads();
#pragma unroll
      for (int p = 0; p < 2; ++p) {
        int e = p * 256 + t;
        int orow = e >> 3, oc = (e & 7) * 8;
        union { uint4 v; u16 s[8]; } tmp;
#pragma unroll
        for (int i = 0; i < 8; ++i) tmp.s[i] = f2u(tile[oc + i][orow]);
        *(uint4*)(outT + (size_t)(c0 + orow) * N + r0 + oc) = tmp.v;
      }
      __syncthreads();  // tile reused next iteration
    }
  }

  __threadfence();  // device-scope: make ws stores visible across XCDs
  cg::this_grid().sync();

  // ---- Phase G1 ----
  {
    u16* lA = (u16*)smem;
    u16* lB = (u16*)(smem + 32768);
    int m0 = (blockIdx.x & 7) * 32;       // F/32 = 8
    int n0 = (blockIdx.x >> 3) * 32;      // N/32 = 64
    gemm32_body<true, false, u16>(lA, lB, xT, Ut, zT, F, N, N, m0, n0,
                                  lam, a, b, c, nullptr, 0.f);
  }

  __threadfence();
  cg::this_grid().sync();

  // ---- Phase G2 ----
  {
    u16* lA = (u16*)smem;
    u16* lB = (u16*)(smem + 32768);
    int m0 = (blockIdx.x & 63) * 32;      // N/32 = 64
    int n0 = (blockIdx.x >> 6) * 32;      // F/32 = 8
    gemm32_body<false, true, float>(lA, lB, Ubf, zT, out, N, F, N, m0, n0,
                                    nullptr, nullptr, nullptr, nullptr,
                                    x, alpha_p[0]);
  }
}

extern "C" void kernel_launch(void* const* d_in, const int* in_sizes, int n_in,
                              void* d_out, int out_size, void* d_ws,
                              size_t ws_size, hipStream_t stream) {
  const float* x = (const float*)d_in[0];     // [N][F] fp32
  const float* lam = (const float*)d_in[1];   // [N][N] fp32 (diag)
  const float* U = (const float*)d_in[2];     // [N][N] fp32
  const float* a = (const float*)d_in[3];
  const float* b = (const float*)d_in[4];
  const float* c = (const float*)d_in[5];
  const float* alpha = (const float*)d_in[6];
  // d_in[7] = edge_index: unused by the reference math

  char* ws = (char*)d_ws;
  u16* xT = (u16*)ws;                          // [F][N] bf16 1 MB
  u16* Ut = (u16*)(ws + (1 << 20));            // [N][N] bf16 (U^T) 8 MB
  u16* Ubf = (u16*)(ws + (9 << 20));           // [N][N] bf16 8 MB
  u16* zT = (u16*)(ws + (17 << 20));           // [F][N] bf16 1 MB
  float* outp = (float*)d_out;

  void* args[] = {&U, &x, &lam, &a, &b, &c, &alpha, &outp,
                  &xT, &Ut, &Ubf, &zT};
  hipLaunchCooperativeKernel((const void*)mega_kernel, dim3(512), dim3(256),
                             args, 0, stream);
}

// Round 9
// 109.041 us; speedup vs baseline: 3.1263x; 3.1263x over previous
//
#include <hip/hip_runtime.h>
#include <type_traits>

typedef unsigned short u16;
typedef __attribute__((ext_vector_type(8))) short short8;
typedef __attribute__((ext_vector_type(4))) float floatx4;

__device__ __forceinline__ u16 f2u(float f) {
  unsigned int x = __float_as_uint(f);
  x += 0x7fff + ((x >> 16) & 1);  // RNE to bf16
  return (u16)(x >> 16);
}

__device__ __forceinline__ void async16(const void* g, void* l) {
  __builtin_amdgcn_global_load_lds(
      (const __attribute__((address_space(1))) unsigned int*)g,
      (__attribute__((address_space(3))) unsigned int*)l, 16, 0, 0);
}

// Transpose+cast, one dispatch, two jobs decoded from blockIdx.x:
//  b < 1024 : U[2048][2048] fp32 -> Ut (transposed bf16) + Ubf (straight bf16)
//  b < 1152 : x[2048][256]  fp32 -> xT[256][2048] bf16
__global__ __launch_bounds__(256) void prep_kernel(
    const float* __restrict__ U, const float* __restrict__ x,
    u16* __restrict__ Ut, u16* __restrict__ Ubf, u16* __restrict__ xT,
    int N, int F) {
  __shared__ __attribute__((aligned(16))) float tile[64][65];
  int bb = blockIdx.x;
  int t = threadIdx.x;

  const float* in;
  u16 *outT, *outC;
  int R, C, c0, r0;
  if (bb < 1024) {  // U job
    in = U; outT = Ut; outC = Ubf; R = N; C = N;
    c0 = (bb & 31) * 64; r0 = (bb >> 5) * 64;
  } else {  // x job
    int b2 = bb - 1024;
    in = x; outT = xT; outC = nullptr; R = N; C = F;
    c0 = (b2 & 3) * 64; r0 = (b2 >> 2) * 64;
  }

#pragma unroll
  for (int p = 0; p < 4; ++p) {
    int e = p * 256 + t;
    int row = e >> 4, col = (e & 15) * 4;
    float4 v = *(const float4*)(in + (size_t)(r0 + row) * C + c0 + col);
    tile[row][col] = v.x;
    tile[row][col + 1] = v.y;
    tile[row][col + 2] = v.z;
    tile[row][col + 3] = v.w;
    if (outC) {
      union { uint2 u; u16 s[4]; } pk;
      pk.s[0] = f2u(v.x); pk.s[1] = f2u(v.y);
      pk.s[2] = f2u(v.z); pk.s[3] = f2u(v.w);
      *(uint2*)(outC + (size_t)(r0 + row) * C + c0 + col) = pk.u;
    }
  }
  __syncthreads();
#pragma unroll
  for (int p = 0; p < 2; ++p) {
    int e = p * 256 + t;
    int orow = e >> 3, oc = (e & 7) * 8;
    union { uint4 v; u16 s[8]; } tmp;
#pragma unroll
    for (int i = 0; i < 8; ++i) tmp.s[i] = f2u(tile[oc + i][orow]);
    *(uint4*)(outT + (size_t)(c0 + orow) * R + r0 + oc) = tmp.v;
  }
}

// Direct TN GEMM (round-7 proven core): C[m][col] = sum_k A[m][k]*B[col][k]
// BM=BN=32; 4 waves 2x2, one 16x16 acc each. Macro BK=256 (8 k32-subtiles),
// double-buffered LDS, ONE barrier per macro (8 total at K=2048).
// 1-D grid of 512 with XCD-aware decode (assumes xcd = b % 8 round-robin):
//  WIDE_N  (GEMM1, 8 m x 64 n): m=(b>>3)&7,        n=(b&7)*8+(b>>6)
//  !WIDE_N (GEMM2, 64 m x 8 n): m=(b&7)*8+(b>>6),  n=(b>>3)&7
// -> each XCD touches a contiguous 8-slab band of the large dimension
//    (1 MB) + the whole small operand (1 MB): fits its 4 MiB L2.
// SCALE_D: *= d(col) inline from lam/pa/pb/pc.
// RESIDUAL: += alpha_p[0]*resid[idx] (fp32).
template <bool WIDE_N, bool SCALE_D, bool RESIDUAL, typename CT>
__global__ __launch_bounds__(256) void gemm32(
    const u16* __restrict__ A, const u16* __restrict__ B, CT* __restrict__ C,
    int M, int NN, int K, const float* __restrict__ lam,
    const float* __restrict__ pa, const float* __restrict__ pb,
    const float* __restrict__ pc, const float* __restrict__ resid,
    const float* __restrict__ alpha_p) {
  __shared__ __attribute__((aligned(16))) u16 lA[2 * 8192];  // 32 KB
  __shared__ __attribute__((aligned(16))) u16 lB[2 * 8192];  // 32 KB
  const int b = blockIdx.x;
  int m0, n0;
  if (WIDE_N) {
    m0 = ((b >> 3) & 7) * 32;
    n0 = ((b & 7) * 8 + (b >> 6)) * 32;
  } else {
    m0 = ((b & 7) * 8 + (b >> 6)) * 32;
    n0 = ((b >> 3) & 7) * 32;
  }
  const int t = threadIdx.x;
  const int wave = t >> 6, lane = t & 63;
  const int wm = wave >> 1, wn = wave & 1;
  const int q = lane >> 4, l15 = lane & 15;

  const int within = t & 127, st0 = t >> 7;  // st0 in {0,1}
  const u16* gA = A + (size_t)(m0 + (within >> 2)) * K + (within & 3) * 8;
  const u16* gB = B + (size_t)(n0 + (within >> 2)) * K + (within & 3) * 8;
  char* lAc = (char*)lA;
  char* lBc = (char*)lB;

  const int NM = K >> 8;  // macro-iters (K/256)

  auto issue = [&](int i, int buf) {
    int k0 = i * 256;
#pragma unroll
    for (int p = 0; p < 4; ++p) {
      int st = 2 * p + st0;
      async16(gA + k0 + st * 32, lAc + buf * 16384 + p * 4096 + t * 16);
      async16(gB + k0 + st * 32, lBc + buf * 16384 + p * 4096 + t * 16);
    }
  };

  floatx4 acc = (floatx4){0.f, 0.f, 0.f, 0.f};

  issue(0, 0);
  for (int i = 0; i < NM; ++i) {
    const int buf = i & 1;
    __syncthreads();  // drains buf's prefetch; all waves done with buf^1
    if (i + 1 < NM) issue(i + 1, buf ^ 1);
    const u16* lAb = lA + buf * 8192;  // u16 units
    const u16* lBb = lB + buf * 8192;
#pragma unroll
    for (int st = 0; st < 8; ++st) {
      short8 af = *(const short8*)&lAb[st * 1024 + (wm * 16 + l15) * 32 + q * 8];
      short8 bf = *(const short8*)&lBb[st * 1024 + (wn * 16 + l15) * 32 + q * 8];
      acc = __builtin_amdgcn_mfma_f32_16x16x32_bf16(af, bf, acc, 0, 0, 0);
    }
  }

  // C/D layout: col=lane&15, row=(lane>>4)*4+reg  [m89/m91]
  const int col = n0 + wn * 16 + l15;
  float ds = 1.f;
  if (SCALE_D) {
    float lv = lam[(size_t)col * NN + col];
    float dacc = 0.f;
#pragma unroll
    for (int i = 0; i < 4; ++i) {
      float ai = pa[i], bi = pb[i], ci = pc[i];
      float rep = (ai - lv) * (lv - bi);
      rep = rep > 0.f ? rep : 0.f;
      dacc += ci * 4.f / ((ai - bi) * (ai - bi)) * rep;
    }
    ds = dacc;
  }
  float alpha = 0.f;
  if (RESIDUAL) alpha = alpha_p[0];
  const int rbase = m0 + wm * 16 + q * 4;
#pragma unroll
  for (int r = 0; r < 4; ++r) {
    float v = acc[r];
    if (SCALE_D) v *= ds;
    size_t idx = (size_t)(rbase + r) * NN + col;
    if (RESIDUAL) v += alpha * resid[idx];
    if constexpr (std::is_same<CT, u16>::value)
      C[idx] = f2u(v);
    else
      C[idx] = v;
  }
}

extern "C" void kernel_launch(void* const* d_in, const int* in_sizes, int n_in,
                              void* d_out, int out_size, void* d_ws,
                              size_t ws_size, hipStream_t stream) {
  const int N = 2048, F = 256;
  const float* x = (const float*)d_in[0];     // [N][F] fp32
  const float* lam = (const float*)d_in[1];   // [N][N] fp32 (diag)
  const float* U = (const float*)d_in[2];     // [N][N] fp32
  const float* a = (const float*)d_in[3];
  const float* b = (const float*)d_in[4];
  const float* c = (const float*)d_in[5];
  const float* alpha = (const float*)d_in[6];
  // d_in[7] = edge_index: unused by the reference math

  char* ws = (char*)d_ws;
  u16* xT = (u16*)ws;                          // [F][N] bf16 1 MB
  u16* Ut = (u16*)(ws + (1 << 20));            // [N][N] bf16 (U^T) 8 MB
  u16* Ubf = (u16*)(ws + (9 << 20));           // [N][N] bf16 8 MB
  u16* zT = (u16*)(ws + (17 << 20));           // [F][N] bf16 1 MB

  // prep: Ut + Ubf + xT in one dispatch
  prep_kernel<<<1152, 256, 0, stream>>>(U, x, Ut, Ubf, xT, N, F);
  // GEMM1: zT[f][j] = d[j] * sum_n xT[f][n]*Ut[j][n]   (bf16 out)
  gemm32<true, true, false, u16><<<512, 256, 0, stream>>>(
      xT, Ut, zT, F, N, N, lam, a, b, c, nullptr, nullptr);
  // GEMM2: out[n][f] = alpha*x[n][f] + sum_j Ubf[n][j]*zT[f][j]  (fp32 out)
  gemm32<false, false, true, float><<<512, 256, 0, stream>>>(
      Ubf, zT, (float*)d_out, N, F, N, nullptr, nullptr, nullptr, nullptr,
      x, alpha);
}

// Round 11
// 108.728 us; speedup vs baseline: 3.1353x; 1.0029x over previous
//
#include <hip/hip_runtime.h>
#include <type_traits>

typedef unsigned short u16;
typedef __attribute__((ext_vector_type(8))) short short8;
typedef __attribute__((ext_vector_type(4))) float floatx4;

__device__ __forceinline__ u16 f2u(float f) {
  unsigned int x = __float_as_uint(f);
  x += 0x7fff + ((x >> 16) & 1);  // RNE to bf16
  return (u16)(x >> 16);
}

__device__ __forceinline__ void async16(const void* g, void* l) {
  __builtin_amdgcn_global_load_lds(
      (const __attribute__((address_space(1))) unsigned int*)g,
      (__attribute__((address_space(3))) unsigned int*)l, 16, 0, 0);
}

// Transpose+cast, one dispatch, two jobs decoded from blockIdx.x:
//  b < 1024 : U[2048][2048] fp32 -> Ut (transposed bf16) + Ubf (straight bf16)
//  b < 1152 : x[2048][256]  fp32 -> xT[256][2048] bf16
__global__ __launch_bounds__(256) void prep_kernel(
    const float* __restrict__ U, const float* __restrict__ x,
    u16* __restrict__ Ut, u16* __restrict__ Ubf, u16* __restrict__ xT,
    int N, int F) {
  __shared__ __attribute__((aligned(16))) float tile[64][65];
  int bb = blockIdx.x;
  int t = threadIdx.x;

  const float* in;
  u16 *outT, *outC;
  int R, C, c0, r0;
  if (bb < 1024) {  // U job
    in = U; outT = Ut; outC = Ubf; R = N; C = N;
    c0 = (bb & 31) * 64; r0 = (bb >> 5) * 64;
  } else {  // x job
    int b2 = bb - 1024;
    in = x; outT = xT; outC = nullptr; R = N; C = F;
    c0 = (b2 & 3) * 64; r0 = (b2 >> 2) * 64;
  }

#pragma unroll
  for (int p = 0; p < 4; ++p) {
    int e = p * 256 + t;
    int row = e >> 4, col = (e & 15) * 4;
    float4 v = *(const float4*)(in + (size_t)(r0 + row) * C + c0 + col);
    tile[row][col] = v.x;
    tile[row][col + 1] = v.y;
    tile[row][col + 2] = v.z;
    tile[row][col + 3] = v.w;
    if (outC) {
      union { uint2 u; u16 s[4]; } pk;
      pk.s[0] = f2u(v.x); pk.s[1] = f2u(v.y);
      pk.s[2] = f2u(v.z); pk.s[3] = f2u(v.w);
      *(uint2*)(outC + (size_t)(r0 + row) * C + c0 + col) = pk.u;
    }
  }
  __syncthreads();
#pragma unroll
  for (int p = 0; p < 2; ++p) {
    int e = p * 256 + t;
    int orow = e >> 3, oc = (e & 7) * 8;
    union { uint4 v; u16 s[8]; } tmp;
#pragma unroll
    for (int i = 0; i < 8; ++i) tmp.s[i] = f2u(tile[oc + i][orow]);
    *(uint4*)(outT + (size_t)(c0 + orow) * R + r0 + oc) = tmp.v;
  }
}

// Direct TN GEMM (round-7 proven core): C[m][col] = sum_k A[m][k]*B[col][k]
// BM=BN=32; 4 waves 2x2, one 16x16 acc each. Macro BK=256 (8 k32-subtiles),
// double-buffered LDS, ONE barrier per macro (8 total at K=2048).
// 1-D grid of 512 with XCD-aware decode (assumes xcd = b % 8 round-robin):
//  WIDE_N  (GEMM1, 8 m x 64 n): m=(b>>3)&7,        n=(b&7)*8+(b>>6)
//  !WIDE_N (GEMM2, 64 m x 8 n): m=(b&7)*8+(b>>6),  n=(b>>3)&7
// -> each XCD touches a contiguous 8-slab band of the large dimension
//    (1 MB) + the whole small operand (1 MB): fits its 4 MiB L2.
// SCALE_D: *= d(col) inline from lam/pa/pb/pc.
// RESIDUAL: += alpha_p[0]*resid[idx] (fp32).
template <bool WIDE_N, bool SCALE_D, bool RESIDUAL, typename CT>
__global__ __launch_bounds__(256) void gemm32(
    const u16* __restrict__ A, const u16* __restrict__ B, CT* __restrict__ C,
    int M, int NN, int K, const float* __restrict__ lam,
    const float* __restrict__ pa, const float* __restrict__ pb,
    const float* __restrict__ pc, const float* __restrict__ resid,
    const float* __restrict__ alpha_p) {
  __shared__ __attribute__((aligned(16))) u16 lA[2 * 8192];  // 32 KB
  __shared__ __attribute__((aligned(16))) u16 lB[2 * 8192];  // 32 KB
  const int b = blockIdx.x;
  int m0, n0;
  if (WIDE_N) {
    m0 = ((b >> 3) & 7) * 32;
    n0 = ((b & 7) * 8 + (b >> 6)) * 32;
  } else {
    m0 = ((b & 7) * 8 + (b >> 6)) * 32;
    n0 = ((b >> 3) & 7) * 32;
  }
  const int t = threadIdx.x;
  const int wave = t >> 6, lane = t & 63;
  const int wm = wave >> 1, wn = wave & 1;
  const int q = lane >> 4, l15 = lane & 15;

  const int within = t & 127, st0 = t >> 7;  // st0 in {0,1}
  const u16* gA = A + (size_t)(m0 + (within >> 2)) * K + (within & 3) * 8;
  const u16* gB = B + (size_t)(n0 + (within >> 2)) * K + (within & 3) * 8;
  char* lAc = (char*)lA;
  char* lBc = (char*)lB;

  const int NM = K >> 8;  // macro-iters (K/256)

  auto issue = [&](int i, int buf) {
    int k0 = i * 256;
#pragma unroll
    for (int p = 0; p < 4; ++p) {
      int st = 2 * p + st0;
      async16(gA + k0 + st * 32, lAc + buf * 16384 + p * 4096 + t * 16);
      async16(gB + k0 + st * 32, lBc + buf * 16384 + p * 4096 + t * 16);
    }
  };

  floatx4 acc = (floatx4){0.f, 0.f, 0.f, 0.f};

  issue(0, 0);
  for (int i = 0; i < NM; ++i) {
    const int buf = i & 1;
    __syncthreads();  // drains buf's prefetch; all waves done with buf^1
    if (i + 1 < NM) issue(i + 1, buf ^ 1);
    const u16* lAb = lA + buf * 8192;  // u16 units
    const u16* lBb = lB + buf * 8192;
#pragma unroll
    for (int st = 0; st < 8; ++st) {
      short8 af = *(const short8*)&lAb[st * 1024 + (wm * 16 + l15) * 32 + q * 8];
      short8 bf = *(const short8*)&lBb[st * 1024 + (wn * 16 + l15) * 32 + q * 8];
      acc = __builtin_amdgcn_mfma_f32_16x16x32_bf16(af, bf, acc, 0, 0, 0);
    }
  }

  // C/D layout: col=lane&15, row=(lane>>4)*4+reg  [m89/m91]
  const int col = n0 + wn * 16 + l15;
  float ds = 1.f;
  if (SCALE_D) {
    float lv = lam[(size_t)col * NN + col];
    float dacc = 0.f;
#pragma unroll
    for (int i = 0; i < 4; ++i) {
      float ai = pa[i], bi = pb[i], ci = pc[i];
      float rep = (ai - lv) * (lv - bi);
      rep = rep > 0.f ? rep : 0.f;
      dacc += ci * 4.f / ((ai - bi) * (ai - bi)) * rep;
    }
    ds = dacc;
  }
  float alpha = 0.f;
  if (RESIDUAL) alpha = alpha_p[0];
  const int rbase = m0 + wm * 16 + q * 4;
#pragma unroll
  for (int r = 0; r < 4; ++r) {
    float v = acc[r];
    if (SCALE_D) v *= ds;
    size_t idx = (size_t)(rbase + r) * NN + col;
    if (RESIDUAL) v += alpha * resid[idx];
    if constexpr (std::is_same<CT, u16>::value)
      C[idx] = f2u(v);
    else
      C[idx] = v;
  }
}

extern "C" void kernel_launch(void* const* d_in, const int* in_sizes, int n_in,
                              void* d_out, int out_size, void* d_ws,
                              size_t ws_size, hipStream_t stream) {
  const int N = 2048, F = 256;
  const float* x = (const float*)d_in[0];     // [N][F] fp32
  const float* lam = (const float*)d_in[1];   // [N][N] fp32 (diag)
  const float* U = (const float*)d_in[2];     // [N][N] fp32
  const float* a = (const float*)d_in[3];
  const float* b = (const float*)d_in[4];
  const float* c = (const float*)d_in[5];
  const float* alpha = (const float*)d_in[6];
  // d_in[7] = edge_index: unused by the reference math

  char* ws = (char*)d_ws;
  u16* xT = (u16*)ws;                          // [F][N] bf16 1 MB
  u16* Ut = (u16*)(ws + (1 << 20));            // [N][N] bf16 (U^T) 8 MB
  u16* Ubf = (u16*)(ws + (9 << 20));           // [N][N] bf16 8 MB
  u16* zT = (u16*)(ws + (17 << 20));           // [F][N] bf16 1 MB

  // prep: Ut + Ubf + xT in one dispatch
  prep_kernel<<<1152, 256, 0, stream>>>(U, x, Ut, Ubf, xT, N, F);
  // GEMM1: zT[f][j] = d[j] * sum_n xT[f][n]*Ut[j][n]   (bf16 out)
  gemm32<true, true, false, u16><<<512, 256, 0, stream>>>(
      xT, Ut, zT, F, N, N, lam, a, b, c, nullptr, nullptr);
  // GEMM2: out[n][f] = alpha*x[n][f] + sum_j Ubf[n][j]*zT[f][j]  (fp32 out)
  gemm32<false, false, true, float><<<512, 256, 0, stream>>>(
      Ubf, zT, (float*)d_out, N, F, N, nullptr, nullptr, nullptr, nullptr,
      x, alpha);
}